// Round 21
// baseline (413.742 us; speedup 1.0000x reference)
//
#include <hip/hip_runtime.h>
#include <hip/hip_bf16.h>

#define NPTS 1000000
#define NSEG 4096
#define ATTCAP 2048

#define KS_ROWS 16
#define LPAD 136      // shorts per LDS row (128 + 8 pad); 136/8 = 17 frags/row

typedef __attribute__((ext_vector_type(8))) short bf16x8;
typedef __attribute__((ext_vector_type(4))) float f32x4;
typedef __attribute__((ext_vector_type(2))) float f32x2;

__device__ __forceinline__ short f2bfs(float f) {
  union { __hip_bfloat16 b; unsigned short s; } u;
  u.b = __float2bfloat16(f);
  return (short)u.s;
}
__device__ __forceinline__ float bf2f(short h) {
  return __uint_as_float(((unsigned)(unsigned short)h) << 16);
}

// channel mapping: ch = 32*wave + (lc>>1)*4 + (lc&1)*2 + c  (c in 0..1)
__device__ __forceinline__ int chbase_of(int wave, int lc) {
  return wave * 32 + (lc >> 1) * 4 + (lc & 1) * 2;
}

// Per-wave 2-col-tile W fragments (64 VGPRs), split hi/lo.
__device__ __forceinline__ void load_w2(const float* __restrict__ Wc, int chb, int lg,
                                        bf16x8 Bh[2][4], bf16x8 Bl[2][4]) {
#pragma unroll
  for (int ks = 0; ks < 4; ++ks) {
#pragma unroll
    for (int j = 0; j < 8; ++j) {
      int k = ks * 32 + lg * 8 + j;
      float2 w2 = *(const float2*)(Wc + (size_t)k * 128 + chb);
      float e[2] = {w2.x, w2.y};
#pragma unroll
      for (int c = 0; c < 2; ++c) {
        short hi = f2bfs(e[c]);
        Bh[c][ks][j] = hi;
        Bl[c][ks][j] = f2bfs(e[c] - bf2f(hi));
      }
    }
  }
}

// convert one float4 to hi/lo short4
__device__ __forceinline__ void cvt4(float4 v, short4& hi, short4& lo) {
  hi.x = f2bfs(v.x); lo.x = f2bfs(v.x - bf2f(hi.x));
  hi.y = f2bfs(v.y); lo.y = f2bfs(v.y - bf2f(hi.y));
  hi.z = f2bfs(v.z); lo.z = f2bfs(v.z - bf2f(hi.z));
  hi.w = f2bfs(v.w); lo.w = f2bfs(v.w - bf2f(hi.w));
}
__device__ __forceinline__ void cvt4v(f32x4 v, short4& hi, short4& lo) {
  hi.x = f2bfs(v[0]); lo.x = f2bfs(v[0] - bf2f(hi.x));
  hi.y = f2bfs(v[1]); lo.y = f2bfs(v[1] - bf2f(hi.y));
  hi.z = f2bfs(v[2]); lo.z = f2bfs(v[2] - bf2f(hi.z));
  hi.w = f2bfs(v[3]); lo.w = f2bfs(v[3] - bf2f(hi.w));
}

// 3-term MFMA for one 16-row subtile read from LDS hi/lo buffers.
__device__ __forceinline__ void mfma_lds(const bf16x8* __restrict__ AHv,
                                         const bf16x8* __restrict__ ALv,
                                         int lc, int lg,
                                         const bf16x8 Bh[2][4], const bf16x8 Bl[2][4],
                                         f32x4 Cf[2]) {
  Cf[0] = (f32x4){0.f, 0.f, 0.f, 0.f};
  Cf[1] = (f32x4){0.f, 0.f, 0.f, 0.f};
#pragma unroll
  for (int ks = 0; ks < 4; ++ks) {
    int fi = lc * 17 + ks * 4 + lg;
    bf16x8 ah = AHv[fi];
    bf16x8 al = ALv[fi];
#pragma unroll
    for (int c = 0; c < 2; ++c) {
      Cf[c] = __builtin_amdgcn_mfma_f32_16x16x32_bf16(ah, Bh[c][ks], Cf[c], 0, 0, 0);
      Cf[c] = __builtin_amdgcn_mfma_f32_16x16x32_bf16(ah, Bl[c][ks], Cf[c], 0, 0, 0);
      Cf[c] = __builtin_amdgcn_mfma_f32_16x16x32_bf16(al, Bh[c][ks], Cf[c], 0, 0, 0);
    }
  }
}

// ===== single kernel: fused (att-in-staging + online stats) GEMM + output GEMM =====
__global__ __launch_bounds__(256, 4) void k_all4(
    const float* __restrict__ x, const float* __restrict__ wp,
    const float* __restrict__ Wc, const float* __restrict__ bc,
    const float* __restrict__ Wa,
    const float* __restrict__ gamma, const float* __restrict__ beta,
    const void* __restrict__ seg, float* __restrict__ out) {

  __shared__ float att_l[ATTCAP];
  __shared__ __align__(16) short AH[2][KS_ROWS * LPAD];
  __shared__ __align__(16) short AL[2][KS_ROWS * LPAD];
  __shared__ float att_d[2][KS_ROWS];
  __shared__ float us[128];
  __shared__ int sm_flag;

  const int t = threadIdx.x;
  const int lane = t & 63;
  const int wave = t >> 6;
  const int lc = lane & 15;
  const int lg = lane >> 4;
  const int chb = chbase_of(wave, lc);
  const int s = blockIdx.x;
  const int* seg32 = (const int*)seg;

  // ---- detect int64 vs int32 segment_idx (probe first 2048) ----
  if (t == 0) sm_flag = 0;
  __syncthreads();
  {
    int any = 0;
#pragma unroll
    for (int k = 0; k < 8; ++k) any |= seg32[2 * (t * 8 + k) + 1];
    if (any) sm_flag = 1;
  }
  __syncthreads();
  const int f64 = (sm_flag == 0);
  __syncthreads();

  // ---- binary search segment range [start, endc) ----
  int blo = 0, bhi = NPTS;
  while (blo < bhi) {
    int mid = (blo + bhi) >> 1;
    int v = f64 ? (int)((const long long*)seg)[mid] : seg32[mid];
    if (v < s) blo = mid + 1; else bhi = mid;
  }
  const int start = blo;
  bhi = NPTS;
  while (blo < bhi) {
    int mid = (blo + bhi) >> 1;
    int v = f64 ? (int)((const long long*)seg)[mid] : seg32[mid];
    if (v < s + 1) blo = mid + 1; else bhi = mid;
  }
  const int endc = min(blo, start + ATTCAP);
  if (start >= endc) return;
  const int len = endc - start;
  const int nt = (len + KS_ROWS - 1) / KS_ROWS;

  // ---- u = Wc . Wa into LDS (att bias cancels in softmax) ----
  if (t < 128) {
    const float4* wa4 = (const float4*)Wa;
    const float4* wr  = (const float4*)(Wc + t * 128);
    float sv = 0.f;
#pragma unroll 8
    for (int c4 = 0; c4 < 32; ++c4) {
      float4 a = wr[c4], b = wa4[c4];
      sv += a.x * b.x + a.y * b.y + a.z * b.z + a.w * b.w;
    }
    us[t] = sv;
  }
  __syncthreads();

  // ---- W fragments + per-channel constants + this thread's u-slice ----
  bf16x8 Bh[2][4], Bl[2][4];
  load_w2(Wc, chb, lg, Bh, Bl);
  float2 bias2 = *(const float2*)(bc + chb);
  float bias_r[2] = {bias2.x, bias2.y};
  const int c4 = t & 31;              // column quad (same for both stg entries)
  const float4 u4 = ((const float4*)us)[c4];

  // helper lambda-ish macro behavior done inline below.

  // ---- fused pass B: stage(+att) dbuf GEMM -> online softmax-weighted stats ----
  float m = -3.0e38f, se = 0.f, sw = 0.f;
  float macc[2] = {0.f, 0.f}, m2cc[2] = {0.f, 0.f};
  {
    float4 stg[2];
    // initial stage of tile 0: load + att + LDS write
#pragma unroll
    for (int i = 0; i < 2; ++i) {
      int idx = t + i * 256, row = idx >> 5;
      int rg = start + row; if (rg >= endc) rg = endc - 1;
      stg[i] = *(const float4*)(x + (size_t)rg * 128 + c4 * 4);
    }
#pragma unroll
    for (int i = 0; i < 2; ++i) {
      int idx = t + i * 256, row = idx >> 5;
      float p = stg[i].x * u4.x + stg[i].y * u4.y + stg[i].z * u4.z + stg[i].w * u4.w;
      p += __shfl_xor(p, 1, 64);
      p += __shfl_xor(p, 2, 64);
      p += __shfl_xor(p, 4, 64);
      p += __shfl_xor(p, 8, 64);
      p += __shfl_xor(p, 16, 64);
      if (c4 == 0) {
        att_d[0][row] = p;
        int rg = start + row;
        if (rg < endc) att_l[rg - start] = p;
      }
      short4 hi, lo;
      cvt4(stg[i], hi, lo);
      *(short4*)&AH[0][row * LPAD + c4 * 4] = hi;
      *(short4*)&AL[0][row * LPAD + c4 * 4] = lo;
    }
    int cur = 0, tl = 0;
    while (1) {
      bool pf = (tl + 1 < nt);
      __syncthreads();                       // buf[cur] + att_d[cur] visible
      if (pf) {
        int rbase = start + (tl + 1) * KS_ROWS;
#pragma unroll
        for (int i = 0; i < 2; ++i) {
          int idx = t + i * 256, row = idx >> 5;
          int rg = rbase + row; if (rg >= endc) rg = endc - 1;
          stg[i] = *(const float4*)(x + (size_t)rg * 128 + c4 * 4);
        }
      }
      {
        f32x4 Cf[2];
        mfma_lds((const bf16x8*)AH[cur], (const bf16x8*)AL[cur], lc, lg, Bh, Bl, Cf);
        int rbase = start + tl * KS_ROWS;
#pragma unroll
        for (int reg = 0; reg < 4; ++reg) {
          int r = lg * 4 + reg;
          int row = rbase + r;
          if (row < endc) {
            float av = att_d[cur][r];
            float nm = fmaxf(m, av);
            float f = __expf(m - nm);
            float e = __expf(av - nm);
            m = nm;
            se = se * f + e;
            float ew = e * wp[row];
            sw = sw * f + ew;
#pragma unroll
            for (int c = 0; c < 2; ++c) {
              float h = Cf[c][reg] + bias_r[c];
              macc[c] = macc[c] * f + ew * h;
              m2cc[c] = m2cc[c] * f + ew * h * h;
            }
          }
        }
      }
      if (!pf) break;
      __syncthreads();                       // buf[cur^1]/att_d[cur^1] free to overwrite
      {
        int rbase = start + (tl + 1) * KS_ROWS;
#pragma unroll
        for (int i = 0; i < 2; ++i) {
          int idx = t + i * 256, row = idx >> 5;
          float p = stg[i].x * u4.x + stg[i].y * u4.y + stg[i].z * u4.z + stg[i].w * u4.w;
          p += __shfl_xor(p, 1, 64);
          p += __shfl_xor(p, 2, 64);
          p += __shfl_xor(p, 4, 64);
          p += __shfl_xor(p, 8, 64);
          p += __shfl_xor(p, 16, 64);
          if (c4 == 0) {
            att_d[cur ^ 1][row] = p;
            int rg = rbase + row;
            if (rg < endc) att_l[rg - start] = p;
          }
          short4 hi, lo;
          cvt4(stg[i], hi, lo);
          *(short4*)&AH[cur ^ 1][row * LPAD + c4 * 4] = hi;
          *(short4*)&AL[cur ^ 1][row * LPAD + c4 * 4] = lo;
        }
      }
      cur ^= 1; ++tl;
    }
  }

  // ---- merge over lg groups (rescaled): each lane ends with global stats ----
#pragma unroll
  for (int o = 16; o <= 32; o <<= 1) {
    float m2  = __shfl_xor(m, o, 64);
    float se2 = __shfl_xor(se, o, 64);
    float sw2 = __shfl_xor(sw, o, 64);
    float a0  = __shfl_xor(macc[0], o, 64);
    float a1  = __shfl_xor(macc[1], o, 64);
    float q0  = __shfl_xor(m2cc[0], o, 64);
    float q1  = __shfl_xor(m2cc[1], o, 64);
    float nm = fmaxf(m, m2);
    float f1 = __expf(m - nm), f2 = __expf(m2 - nm);
    se = se * f1 + se2 * f2;
    sw = sw * f1 + sw2 * f2;
    macc[0] = macc[0] * f1 + a0 * f2;
    macc[1] = macc[1] * f1 + a1 * f2;
    m2cc[0] = m2cc[0] * f1 + q0 * f2;
    m2cc[1] = m2cc[1] * f1 + q1 * f2;
    m = nm;
  }
  const float ratio = sw / se;
  const float dn = fmaxf(ratio, 1e-3f);
  const float ka = 1.f / (se * dn);
  const float Sa = ratio / dn;
  float mean_r[2], isd_r[2];
#pragma unroll
  for (int c = 0; c < 2; ++c) {
    float mn = macc[c] * ka;
    float M2 = m2cc[c] * ka;
    float var = M2 - mn * mn * (2.f - Sa);
    mean_r[c] = mn;
    isd_r[c] = 1.f / sqrtf(var + 1e-3f);
  }
  __syncthreads();   // att_l complete; pass-B LDS free

  // ---- 'a' output (non-temporal) ----
  for (int i = t; i < len; i += 256) {
    float a = __expf(att_l[i] - m) * wp[start + i] * ka;
    __builtin_nontemporal_store(a, out + (size_t)NPTS * 128 + start + i);
  }

  // ---- pass C: staged dbuf GEMM (NT loads) -> normalize + pair-GN + ReLU + NT store ----
  float2 gam2 = *(const float2*)(gamma + chb);
  float2 bet2 = *(const float2*)(beta  + chb);
  {
    f32x4 stg[2];
#pragma unroll
    for (int i = 0; i < 2; ++i) {
      int idx = t + i * 256, row = idx >> 5;
      int rg = start + row; if (rg >= endc) rg = endc - 1;
      stg[i] = __builtin_nontemporal_load((const f32x4*)(x + (size_t)rg * 128 + c4 * 4));
    }
#pragma unroll
    for (int i = 0; i < 2; ++i) {
      int idx = t + i * 256, row = idx >> 5;
      short4 hi, lo;
      cvt4v(stg[i], hi, lo);
      *(short4*)&AH[0][row * LPAD + c4 * 4] = hi;
      *(short4*)&AL[0][row * LPAD + c4 * 4] = lo;
    }
    int cur = 0, tl = 0;
    while (1) {
      bool pf = (tl + 1 < nt);
      __syncthreads();
      if (pf) {
        int rbase = start + (tl + 1) * KS_ROWS;
#pragma unroll
        for (int i = 0; i < 2; ++i) {
          int idx = t + i * 256, row = idx >> 5;
          int rg = rbase + row; if (rg >= endc) rg = endc - 1;
          stg[i] = __builtin_nontemporal_load((const f32x4*)(x + (size_t)rg * 128 + c4 * 4));
        }
      }
      {
        f32x4 Cf[2];
        mfma_lds((const bf16x8*)AH[cur], (const bf16x8*)AL[cur], lc, lg, Bh, Bl, Cf);
        int rbase = start + tl * KS_ROWS;
#pragma unroll
        for (int reg = 0; reg < 4; ++reg) {
          int row = rbase + lg * 4 + reg;
          float o0 = (Cf[0][reg] + bias_r[0] - mean_r[0]) * isd_r[0];
          float o1 = (Cf[1][reg] + bias_r[1] - mean_r[1]) * isd_r[1];
          float sp = o0 + o1;
          float qp = o0 * o0 + o1 * o1;
          float s4 = sp + __shfl_xor(sp, 1, 64);
          float q4 = qp + __shfl_xor(qp, 1, 64);
          float mu = 0.25f * s4, msq = 0.25f * q4;
          float gsc = 1.f / sqrtf(msq - mu * mu + 1e-5f);
          if (row < endc) {
            f32x2 v;
            v[0] = fmaxf((o0 - mu) * gsc * gam2.x + bet2.x, 0.f);
            v[1] = fmaxf((o1 - mu) * gsc * gam2.y + bet2.y, 0.f);
            __builtin_nontemporal_store(v, (f32x2*)(out + (size_t)row * 128 + chb));
          }
        }
      }
      if (!pf) break;
      __syncthreads();
#pragma unroll
      for (int i = 0; i < 2; ++i) {
        int idx = t + i * 256, row = idx >> 5;
        short4 hi, lo;
        cvt4v(stg[i], hi, lo);
        *(short4*)&AH[cur ^ 1][row * LPAD + c4 * 4] = hi;
        *(short4*)&AL[cur ^ 1][row * LPAD + c4 * 4] = lo;
      }
      cur ^= 1; ++tl;
    }
  }
}

extern "C" void kernel_launch(void* const* d_in, const int* in_sizes, int n_in,
                              void* d_out, int out_size, void* d_ws, size_t ws_size,
                              hipStream_t stream) {
  // 0:x 1:weight_pri 2:W_conv 3:b_conv 4:W_att 5:b_att 6:gamma 7:beta 8:segment_idx
  const float* x    = (const float*)d_in[0];
  const float* wpri = (const float*)d_in[1];
  const float* Wc   = (const float*)d_in[2];
  const float* bc   = (const float*)d_in[3];
  const float* Wa   = (const float*)d_in[4];
  const float* gm   = (const float*)d_in[6];
  const float* bt   = (const float*)d_in[7];
  const void*  seg  = d_in[8];
  float* out = (float*)d_out;
  (void)in_sizes; (void)n_in; (void)out_size; (void)d_ws; (void)ws_size;

  k_all4<<<NSEG, 256, 0, stream>>>(x, wpri, Wc, bc, Wa, gm, bt, seg, out);
}

// Round 22
// 374.726 us; speedup vs baseline: 1.1041x; 1.1041x over previous
//
#include <hip/hip_runtime.h>
#include <hip/hip_bf16.h>

#define NPTS 1000000
#define NSEG 4096
#define ATTCAP 2048

#define KS_ROWS 16
#define LPAD 136      // shorts per LDS row (128 + 8 pad); 136/8 = 17 frags/row

typedef __attribute__((ext_vector_type(8))) short bf16x8;
typedef __attribute__((ext_vector_type(4))) float f32x4;
typedef __attribute__((ext_vector_type(2))) float f32x2;

__device__ __forceinline__ short f2bfs(float f) {
  union { __hip_bfloat16 b; unsigned short s; } u;
  u.b = __float2bfloat16(f);
  return (short)u.s;
}
__device__ __forceinline__ float bf2f(short h) {
  return __uint_as_float(((unsigned)(unsigned short)h) << 16);
}
__device__ __forceinline__ void online_merge(float& m, float& se, float& sw,
                                             float m2, float se2, float sw2) {
  float nm = fmaxf(m, m2);
  float f1 = __expf(m - nm), f2 = __expf(m2 - nm);
  se = se * f1 + se2 * f2;
  sw = sw * f1 + sw2 * f2;
  m = nm;
}

// channel mapping: ch = 32*wave + (lc>>1)*4 + (lc&1)*2 + c  (c in 0..1)
__device__ __forceinline__ int chbase_of(int wave, int lc) {
  return wave * 32 + (lc >> 1) * 4 + (lc & 1) * 2;
}

// Per-wave 2-col-tile W fragments (64 VGPRs), split hi/lo.
__device__ __forceinline__ void load_w2(const float* __restrict__ Wc, int chb, int lg,
                                        bf16x8 Bh[2][4], bf16x8 Bl[2][4]) {
#pragma unroll
  for (int ks = 0; ks < 4; ++ks) {
#pragma unroll
    for (int j = 0; j < 8; ++j) {
      int k = ks * 32 + lg * 8 + j;
      float2 w2 = *(const float2*)(Wc + (size_t)k * 128 + chb);
      float e[2] = {w2.x, w2.y};
#pragma unroll
      for (int c = 0; c < 2; ++c) {
        short hi = f2bfs(e[c]);
        Bh[c][ks][j] = hi;
        Bl[c][ks][j] = f2bfs(e[c] - bf2f(hi));
      }
    }
  }
}

// convert one float4 to hi/lo short4
__device__ __forceinline__ void cvt4(float4 v, short4& hi, short4& lo) {
  hi.x = f2bfs(v.x); lo.x = f2bfs(v.x - bf2f(hi.x));
  hi.y = f2bfs(v.y); lo.y = f2bfs(v.y - bf2f(hi.y));
  hi.z = f2bfs(v.z); lo.z = f2bfs(v.z - bf2f(hi.z));
  hi.w = f2bfs(v.w); lo.w = f2bfs(v.w - bf2f(hi.w));
}

// convert one f32x4 (ext vector) to hi/lo short4
__device__ __forceinline__ void cvt4v(f32x4 v, short4& hi, short4& lo) {
  hi.x = f2bfs(v[0]); lo.x = f2bfs(v[0] - bf2f(hi.x));
  hi.y = f2bfs(v[1]); lo.y = f2bfs(v[1] - bf2f(hi.y));
  hi.z = f2bfs(v[2]); lo.z = f2bfs(v[2] - bf2f(hi.z));
  hi.w = f2bfs(v[3]); lo.w = f2bfs(v[3] - bf2f(hi.w));
}

// 3-term MFMA for one 16-row subtile read from LDS hi/lo buffers.
__device__ __forceinline__ void mfma_lds(const bf16x8* __restrict__ AHv,
                                         const bf16x8* __restrict__ ALv,
                                         int lc, int lg,
                                         const bf16x8 Bh[2][4], const bf16x8 Bl[2][4],
                                         f32x4 Cf[2]) {
  Cf[0] = (f32x4){0.f, 0.f, 0.f, 0.f};
  Cf[1] = (f32x4){0.f, 0.f, 0.f, 0.f};
#pragma unroll
  for (int ks = 0; ks < 4; ++ks) {
    int fi = lc * 17 + ks * 4 + lg;
    bf16x8 ah = AHv[fi];
    bf16x8 al = ALv[fi];
#pragma unroll
    for (int c = 0; c < 2; ++c) {
      Cf[c] = __builtin_amdgcn_mfma_f32_16x16x32_bf16(ah, Bh[c][ks], Cf[c], 0, 0, 0);
      Cf[c] = __builtin_amdgcn_mfma_f32_16x16x32_bf16(ah, Bl[c][ks], Cf[c], 0, 0, 0);
      Cf[c] = __builtin_amdgcn_mfma_f32_16x16x32_bf16(al, Bh[c][ks], Cf[c], 0, 0, 0);
    }
  }
}

// ===== single kernel: att + softmax + 'a' + stats GEMM + output GEMM =====
__global__ __launch_bounds__(256, 4) void k_all2(
    const float* __restrict__ x, const float* __restrict__ wp,
    const float* __restrict__ Wc, const float* __restrict__ bc,
    const float* __restrict__ Wa,
    const float* __restrict__ gamma, const float* __restrict__ beta,
    const void* __restrict__ seg, float* __restrict__ out) {

  __shared__ float att_l[ATTCAP];
  __shared__ __align__(16) short AH[2][KS_ROWS * LPAD];
  __shared__ __align__(16) short AL[2][KS_ROWS * LPAD];
  __shared__ float us[128];
  __shared__ float sm_red[12];
  __shared__ int sm_flag;

  const int t = threadIdx.x;
  const int lane = t & 63;
  const int wave = t >> 6;
  const int lc = lane & 15;
  const int lg = lane >> 4;
  const int chb = chbase_of(wave, lc);
  const int s = blockIdx.x;
  const int* seg32 = (const int*)seg;

  // ---- detect int64 vs int32 segment_idx (probe first 2048) ----
  if (t == 0) sm_flag = 0;
  __syncthreads();
  {
    int any = 0;
#pragma unroll
    for (int k = 0; k < 8; ++k) any |= seg32[2 * (t * 8 + k) + 1];
    if (any) sm_flag = 1;
  }
  __syncthreads();
  const int f64 = (sm_flag == 0);
  __syncthreads();

  // ---- binary search segment range [start, endc) ----
  int blo = 0, bhi = NPTS;
  while (blo < bhi) {
    int mid = (blo + bhi) >> 1;
    int v = f64 ? (int)((const long long*)seg)[mid] : seg32[mid];
    if (v < s) blo = mid + 1; else bhi = mid;
  }
  const int start = blo;
  bhi = NPTS;
  while (blo < bhi) {
    int mid = (blo + bhi) >> 1;
    int v = f64 ? (int)((const long long*)seg)[mid] : seg32[mid];
    if (v < s + 1) blo = mid + 1; else bhi = mid;
  }
  const int endc = min(blo, start + ATTCAP);
  if (start >= endc) return;
  const int len = endc - start;

  // ---- u = Wc . Wa  (att projection; additive bias cancels in softmax) ----
  if (t < 128) {
    const float4* wa4 = (const float4*)Wa;
    const float4* wr  = (const float4*)(Wc + t * 128);
    float sv = 0.f;
#pragma unroll 8
    for (int c4 = 0; c4 < 32; ++c4) {
      float4 a = wr[c4], b = wa4[c4];
      sv += a.x * b.x + a.y * b.y + a.z * b.z + a.w * b.w;
    }
    us[t] = sv;
  }
  __syncthreads();

  // ---- pass A': att = x . u over this segment's rows (octet dot) ----
  {
    const int q8 = t & 7;
    float ur[16];
#pragma unroll
    for (int j = 0; j < 16; ++j) ur[j] = us[q8 * 16 + j];
    for (int r0 = start; r0 < endc; r0 += 32) {
      int row = r0 + (t >> 3);
      int ra = row < NPTS ? row : NPTS - 1;
      const float4* xp = (const float4*)(x + (size_t)ra * 128 + q8 * 16);
      float4 a0 = xp[0], b0 = xp[1], c0 = xp[2], d0 = xp[3];
      float sv = a0.x*ur[0] + a0.y*ur[1] + a0.z*ur[2] + a0.w*ur[3]
               + b0.x*ur[4] + b0.y*ur[5] + b0.z*ur[6] + b0.w*ur[7]
               + c0.x*ur[8] + c0.y*ur[9] + c0.z*ur[10]+ c0.w*ur[11]
               + d0.x*ur[12]+ d0.y*ur[13]+ d0.z*ur[14]+ d0.w*ur[15];
      sv += __shfl_xor(sv, 1, 64);
      sv += __shfl_xor(sv, 2, 64);
      sv += __shfl_xor(sv, 4, 64);
      if (q8 == 0 && row < endc) att_l[row - start] = sv;
    }
  }
  __syncthreads();

  // ---- softmax stats; write 'a' output (non-temporal); a -> att_l ----
  float m = -3.0e38f, se = 0.f, sw = 0.f;
  for (int i = t; i < len; i += 256) {
    float av = att_l[i], w = wp[start + i];
    float nm = fmaxf(m, av);
    float sc = __expf(m - nm), e = __expf(av - nm);
    se = se * sc + e;
    sw = sw * sc + e * w;
    m = nm;
  }
#pragma unroll
  for (int o = 1; o < 64; o <<= 1)
    online_merge(m, se, sw, __shfl_xor(m, o, 64), __shfl_xor(se, o, 64), __shfl_xor(sw, o, 64));
  if (lane == 0) { sm_red[wave] = m; sm_red[4 + wave] = se; sm_red[8 + wave] = sw; }
  __syncthreads();
  float gmx = sm_red[0], gse = sm_red[4], gsw = sm_red[8];
#pragma unroll
  for (int i = 1; i < 4; ++i) online_merge(gmx, gse, gsw, sm_red[i], sm_red[4 + i], sm_red[8 + i]);
  const float ratio = gsw / gse;
  const float dn = fmaxf(ratio, 1e-3f);
  const float ka = 1.f / (gse * dn);
  const float Sa = ratio / dn;
  for (int i = t; i < len; i += 256) {
    float a = __expf(att_l[i] - gmx) * wp[start + i] * ka;
    att_l[i] = a;
    __builtin_nontemporal_store(a, out + (size_t)NPTS * 128 + start + i);
  }
  __syncthreads();

  // ---- W fragments + per-channel constants ----
  bf16x8 Bh[2][4], Bl[2][4];
  load_w2(Wc, chb, lg, Bh, Bl);
  float2 bias2 = *(const float2*)(bc    + chb);
  float2 gam2  = *(const float2*)(gamma + chb);
  float2 bet2  = *(const float2*)(beta  + chb);
  float bias_r[2] = {bias2.x, bias2.y};

  const int nt = (len + KS_ROWS - 1) / KS_ROWS;

  // ---- pass B: staged dbuf GEMM -> weighted mean / M2 ----
  float macc[2] = {0.f, 0.f}, m2cc[2] = {0.f, 0.f};
  {
    float4 stg[2];
#pragma unroll
    for (int i = 0; i < 2; ++i) {
      int idx = t + i * 256, row = idx >> 5, c4 = idx & 31;
      int rg = start + row; if (rg >= endc) rg = endc - 1;
      stg[i] = *(const float4*)(x + (size_t)rg * 128 + c4 * 4);
    }
#pragma unroll
    for (int i = 0; i < 2; ++i) {
      int idx = t + i * 256, row = idx >> 5, c4 = idx & 31;
      short4 hi, lo;
      cvt4(stg[i], hi, lo);
      *(short4*)&AH[0][row * LPAD + c4 * 4] = hi;
      *(short4*)&AL[0][row * LPAD + c4 * 4] = lo;
    }
    int cur = 0, tl = 0;
    while (1) {
      bool pf = (tl + 1 < nt);
      __syncthreads();
      if (pf) {
        int rbase = start + (tl + 1) * KS_ROWS;
#pragma unroll
        for (int i = 0; i < 2; ++i) {
          int idx = t + i * 256, row = idx >> 5, c4 = idx & 31;
          int rg = rbase + row; if (rg >= endc) rg = endc - 1;
          stg[i] = *(const float4*)(x + (size_t)rg * 128 + c4 * 4);
        }
      }
      {
        f32x4 Cf[2];
        mfma_lds((const bf16x8*)AH[cur], (const bf16x8*)AL[cur], lc, lg, Bh, Bl, Cf);
        int rbase = start + tl * KS_ROWS;
#pragma unroll
        for (int reg = 0; reg < 4; ++reg) {
          int row = rbase + lg * 4 + reg;
          float a = (row < endc) ? att_l[row - start] : 0.f;
#pragma unroll
          for (int c = 0; c < 2; ++c) {
            float h = Cf[c][reg] + bias_r[c];
            macc[c] += a * h;
            m2cc[c] += a * h * h;
          }
        }
      }
      if (!pf) break;
      __syncthreads();
#pragma unroll
      for (int i = 0; i < 2; ++i) {
        int idx = t + i * 256, row = idx >> 5, c4 = idx & 31;
        short4 hi, lo;
        cvt4(stg[i], hi, lo);
        *(short4*)&AH[cur ^ 1][row * LPAD + c4 * 4] = hi;
        *(short4*)&AL[cur ^ 1][row * LPAD + c4 * 4] = lo;
      }
      cur ^= 1; ++tl;
    }
  }

  // ---- cross-lane reduce (lg groups) -> mean/isd in registers (all lanes) ----
#pragma unroll
  for (int c = 0; c < 2; ++c) {
    macc[c] += __shfl_xor(macc[c], 16, 64);
    macc[c] += __shfl_xor(macc[c], 32, 64);
    m2cc[c] += __shfl_xor(m2cc[c], 16, 64);
    m2cc[c] += __shfl_xor(m2cc[c], 32, 64);
  }
  float mean_r[2], isd_r[2];
#pragma unroll
  for (int c = 0; c < 2; ++c) {
    float var = m2cc[c] - macc[c] * macc[c] * (2.f - Sa);
    mean_r[c] = macc[c];
    isd_r[c] = 1.f / sqrtf(var + 1e-3f);
  }
  __syncthreads();   // all waves done with pass-B LDS before pass C restages

  // ---- pass C: staged dbuf GEMM (NT loads) -> normalize + pair-GN + ReLU + NT store ----
  {
    f32x4 stg[2];
#pragma unroll
    for (int i = 0; i < 2; ++i) {
      int idx = t + i * 256, row = idx >> 5, c4 = idx & 31;
      int rg = start + row; if (rg >= endc) rg = endc - 1;
      stg[i] = __builtin_nontemporal_load((const f32x4*)(x + (size_t)rg * 128 + c4 * 4));
    }
#pragma unroll
    for (int i = 0; i < 2; ++i) {
      int idx = t + i * 256, row = idx >> 5, c4 = idx & 31;
      short4 hi, lo;
      cvt4v(stg[i], hi, lo);
      *(short4*)&AH[0][row * LPAD + c4 * 4] = hi;
      *(short4*)&AL[0][row * LPAD + c4 * 4] = lo;
    }
    int cur = 0, tl = 0;
    while (1) {
      bool pf = (tl + 1 < nt);
      __syncthreads();
      if (pf) {
        int rbase = start + (tl + 1) * KS_ROWS;
#pragma unroll
        for (int i = 0; i < 2; ++i) {
          int idx = t + i * 256, row = idx >> 5, c4 = idx & 31;
          int rg = rbase + row; if (rg >= endc) rg = endc - 1;
          stg[i] = __builtin_nontemporal_load((const f32x4*)(x + (size_t)rg * 128 + c4 * 4));
        }
      }
      {
        f32x4 Cf[2];
        mfma_lds((const bf16x8*)AH[cur], (const bf16x8*)AL[cur], lc, lg, Bh, Bl, Cf);
        int rbase = start + tl * KS_ROWS;
#pragma unroll
        for (int reg = 0; reg < 4; ++reg) {
          int row = rbase + lg * 4 + reg;
          float o0 = (Cf[0][reg] + bias_r[0] - mean_r[0]) * isd_r[0];
          float o1 = (Cf[1][reg] + bias_r[1] - mean_r[1]) * isd_r[1];
          float sp = o0 + o1;
          float qp = o0 * o0 + o1 * o1;
          float s4 = sp + __shfl_xor(sp, 1, 64);
          float q4 = qp + __shfl_xor(qp, 1, 64);
          float mu = 0.25f * s4, msq = 0.25f * q4;
          float gsc = 1.f / sqrtf(msq - mu * mu + 1e-5f);
          if (row < endc) {
            f32x2 v;
            v[0] = fmaxf((o0 - mu) * gsc * gam2.x + bet2.x, 0.f);
            v[1] = fmaxf((o1 - mu) * gsc * gam2.y + bet2.y, 0.f);
            __builtin_nontemporal_store(v, (f32x2*)(out + (size_t)row * 128 + chb));
          }
        }
      }
      if (!pf) break;
      __syncthreads();
#pragma unroll
      for (int i = 0; i < 2; ++i) {
        int idx = t + i * 256, row = idx >> 5, c4 = idx & 31;
        short4 hi, lo;
        cvt4v(stg[i], hi, lo);
        *(short4*)&AH[cur ^ 1][row * LPAD + c4 * 4] = hi;
        *(short4*)&AL[cur ^ 1][row * LPAD + c4 * 4] = lo;
      }
      cur ^= 1; ++tl;
    }
  }
}

extern "C" void kernel_launch(void* const* d_in, const int* in_sizes, int n_in,
                              void* d_out, int out_size, void* d_ws, size_t ws_size,
                              hipStream_t stream) {
  // 0:x 1:weight_pri 2:W_conv 3:b_conv 4:W_att 5:b_att 6:gamma 7:beta 8:segment_idx
  const float* x    = (const float*)d_in[0];
  const float* wpri = (const float*)d_in[1];
  const float* Wc   = (const float*)d_in[2];
  const float* bc   = (const float*)d_in[3];
  const float* Wa   = (const float*)d_in[4];
  const float* gm   = (const float*)d_in[6];
  const float* bt   = (const float*)d_in[7];
  const void*  seg  = d_in[8];
  float* out = (float*)d_out;
  (void)in_sizes; (void)n_in; (void)out_size; (void)d_ws; (void)ws_size;

  k_all2<<<NSEG, 256, 0, stream>>>(x, wpri, Wc, bc, Wa, gm, bt, seg, out);
}